// Round 7
// baseline (267.703 us; speedup 1.0000x reference)
//
#include <hip/hip_runtime.h>
#include <math.h>

#define NPGN 61
#define NGRAPH 128
#define NNODES (NPGN*NGRAPH)   // 7808
#define EPG 3660               // 61*60 edges per graph

typedef float float4v __attribute__((ext_vector_type(4)));
typedef short bf16x8 __attribute__((ext_vector_type(8)));
typedef short shortx4 __attribute__((ext_vector_type(4)));
typedef unsigned short u16;

__device__ __forceinline__ u16 f2bf(float v){
  union { float f; unsigned u; } x; x.f = v;
  unsigned r = (x.u + 0x7FFFu + ((x.u >> 16) & 1u)) >> 16;
  return (u16)r;
}
__device__ __forceinline__ float bf2f(unsigned u){
  union { unsigned u; float f; } x; x.u = u << 16;
  return x.f;
}

// ---------------- fused prep: weight re-layouts + lw0 transpose + edge tanh -
// blocks [0,296): w-layouts ; [296,540): lw0t ; [540,769): edge weights
__global__ __launch_bounds__(256) void k_prep(const float* __restrict__ w0,
    const float* __restrict__ w1, const float* __restrict__ w2,
    const float* __restrict__ gw0, const float* __restrict__ gw1, const float* __restrict__ gw2,
    const float* __restrict__ lw0, const float* __restrict__ ef,
    const float* __restrict__ eww, const float* __restrict__ ewb,
    u16* __restrict__ w0p, u16* __restrict__ w1b, u16* __restrict__ w2b,
    u16* __restrict__ gwt0, u16* __restrict__ gwt1, u16* __restrict__ gwt2,
    u16* __restrict__ lw0t, float* __restrict__ ew, float* __restrict__ out2){
  __shared__ __align__(16) unsigned char pbuf[8448];
  int b = blockIdx.x, tid = threadIdx.x;
  if (b < 296){
    int idx = b*256 + tid;
    if (idx < 20480){
      int f = idx / 320, r = idx - f*320;
      int kk = r >> 6, c = r & 63;
      w1b[idx] = f2bf(w1[f*320 + c*5 + kk]);
    } else if (idx < 32768){
      int j = idx - 20480; w2b[j] = f2bf(w2[j]);
    } else if (idx < 40960){
      int j = idx - 32768; int jj = j >> 6, k = j & 63; gwt0[j] = f2bf(gw0[k*128 + jj]);
    } else if (idx < 57344){
      int j = idx - 40960; int jj = j >> 7, k = j & 127; gwt1[j] = f2bf(gw1[k*128 + jj]);
    } else if (idx < 73728){
      int j = idx - 57344; int jj = j >> 7, k = j & 127; gwt2[j] = f2bf(gw2[k*128 + jj]);
    } else if (idx < 75776){
      int j = idx - 73728; int f = j >> 5, k = j & 31;
      w0p[j] = (k < 7) ? f2bf(w0[f*7 + k]) : (u16)0;
    }
  } else if (b < 540){
    int bb = b - 296;
    int i = bb >> 2, oq = bb & 3;      // o-chunk of 32
    u16* tile = (u16*)pbuf;            // 32 x 132
    for (int idx = tid; idx < 4096; idx += 256){
      int k = idx >> 5, ol = idx & 31;
      tile[ol*132 + k] = f2bf(lw0[((size_t)i*128 + k)*128 + oq*32 + ol]);
    }
    __syncthreads();
    unsigned* dst = (unsigned*)lw0t;
    for (int idx = tid; idx < 2048; idx += 256){
      int ol = idx >> 6, kw = idx & 63;
      unsigned v = (unsigned)tile[ol*132 + 2*kw] | ((unsigned)tile[ol*132 + 2*kw + 1] << 16);
      dst[((size_t)i*128 + oq*32 + ol)*64 + kw] = v;
    }
  } else {
    int jb = b - 540;
    int i0 = jb*16;
    float v0 = eww[0], v1 = eww[1], v2 = eww[2], bb = ewb[0];
    float (*t)[129] = (float(*)[129])pbuf;   // 16 x 129 fp32
    #pragma unroll 1
    for (int it = 0; it < 8; it++){
      int idx = it*256 + tid;
      int g = idx >> 4, ii = idx & 15;
      int i = i0 + ii;
      if (i < EPG){
        size_t e = (size_t)g*EPG + i;
        const float* p = ef + e*3;
        float v = tanhf(p[0]*v0 + p[1]*v1 + p[2]*v2 + bb);
        ew[e] = v;
        t[ii][g] = v;
      }
    }
    __syncthreads();
    #pragma unroll 1
    for (int it = 0; it < 8; it++){
      int idx = it*256 + tid;
      int ii = idx >> 7, g = idx & 127;
      int i = i0 + ii;
      if (i < EPG) out2[(size_t)i*128 + g] = t[ii][g];
    }
  }
}

// ---------------- dense per-graph edge matrix, bf16, [g][64][72] ------------
#define EW_STR 72
__global__ __launch_bounds__(256) void k_ewmat(const float* __restrict__ ew, u16* __restrict__ ewg_bf){
  int g = blockIdx.x, tid = threadIdx.x;
  __shared__ u16 t[64*EW_STR];
  unsigned* td = (unsigned*)t;
  for (int idx = tid; idx < 64*EW_STR/2; idx += 256) td[idx] = 0;
  __syncthreads();
  const float* e = ew + (size_t)g*EPG;
  for (int idx = tid; idx < EPG; idx += 256){
    int s = idx/60, r = idx - s*60;
    int d = r + (r >= s ? 1 : 0);
    t[d*EW_STR + s] = f2bf(e[idx]);
  }
  __syncthreads();
  unsigned* dst = (unsigned*)ewg_bf + (size_t)g*(64*EW_STR/2);
  for (int idx = tid; idx < 64*EW_STR/2; idx += 256) dst[idx] = td[idx];
}

// ---------------- conv stack: 4 independent waves/block, 1 node/wave --------
#define A0T_STR 72   // u16 units (144 B)
#define C1_STR 40    // u16 units (80 B)
#define XSH_STR 256  // u16 per shifted copy
__global__ __launch_bounds__(256) void k_conv(const float* __restrict__ x,
    const u16* __restrict__ w0p, const float* __restrict__ b0,
    const u16* __restrict__ w1b, const float* __restrict__ b1,
    const u16* __restrict__ w2b, const float* __restrict__ b2,
    float* __restrict__ h0){
  int w = threadIdx.x >> 6, lane = threadIdx.x & 63;
  int n = blockIdx.x*4 + w;
  int q = lane >> 4, r16 = lane & 15;
  __shared__ __align__(16) u16 xsh_s[4][4*XSH_STR];
  __shared__ __align__(16) u16 a0t_s[4][36*A0T_STR];
  __shared__ __align__(16) u16 a1k_s[4][208];
  u16* xsh = xsh_s[w];
  u16* a0t = a0t_s[w];
  u16* a1k = a1k_s[w];

  {
    unsigned* xz = (unsigned*)xsh;
    #pragma unroll
    for (int t = 0; t < 8; t++) xz[lane + 64*t] = 0;
  }
  const float* xrow = x + (size_t)n*160;
  if (lane < 40){
    float4 f0 = *(const float4*)(xrow + 4*lane);
    float e4 = 0.f, e5 = 0.f, e6 = 0.f;
    if (lane < 39){ e4 = xrow[4*lane+4]; e5 = xrow[4*lane+5]; e6 = xrow[4*lane+6]; }
    u16 xb[7];
    xb[0]=f2bf(f0.x); xb[1]=f2bf(f0.y); xb[2]=f2bf(f0.z); xb[3]=f2bf(f0.w);
    xb[4]=f2bf(e4);   xb[5]=f2bf(e5);   xb[6]=f2bf(e6);
    #pragma unroll
    for (int b = 0; b < 4; b++){
      unsigned* dst = (unsigned*)(xsh + b*XSH_STR);
      dst[2*lane]   = (unsigned)xb[b]   | ((unsigned)xb[b+1] << 16);
      dst[2*lane+1] = (unsigned)xb[b+2] | ((unsigned)xb[b+3] << 16);
    }
  }
  {
    unsigned* a0z = (unsigned*)a0t;
    #pragma unroll
    for (int t = 0; t < 7; t++){
      int idx = t*64 + lane;
      int rr = idx >> 5, cc = idx & 31;
      int row = rr < 2 ? rr : 22 + rr;
      a0z[row*36 + cc] = 0;
    }
  }

  // conv0 MFMA: 7 passes (r = intra-pool offset), nt OUTER (rmax[4] only)
  bf16x8 a0f[4];
  #pragma unroll
  for (int mt = 0; mt < 4; mt++)
    a0f[mt] = *(const bf16x8*)(w0p + (16*mt + r16)*32 + q*8);
  #pragma unroll
  for (int nt = 0; nt < 2; nt++){
    float4v rmax[4];
    #pragma unroll
    for (int r = 0; r < 7; r++){
      int o = 112*nt + 7*r16 + r + 8*q;
      int bsh = o & 3, idx = o - bsh;
      const u16* base = xsh + bsh*XSH_STR + idx;
      shortx4 lo = *(const shortx4*)(base);
      shortx4 hi = *(const shortx4*)(base + 4);
      bf16x8 bb;
      bb[0]=lo[0]; bb[1]=lo[1]; bb[2]=lo[2]; bb[3]=lo[3];
      bb[4]=hi[0]; bb[5]=hi[1]; bb[6]=hi[2]; bb[7]=hi[3];
      #pragma unroll
      for (int mt = 0; mt < 4; mt++){
        float4v t = __builtin_amdgcn_mfma_f32_16x16x32_bf16(a0f[mt], bb,
                        (float4v){0.f,0.f,0.f,0.f}, 0, 0, 0);
        if (r == 0) rmax[mt] = t;
        else {
          rmax[mt][0] = fmaxf(rmax[mt][0], t[0]);
          rmax[mt][1] = fmaxf(rmax[mt][1], t[1]);
          rmax[mt][2] = fmaxf(rmax[mt][2], t[2]);
          rmax[mt][3] = fmaxf(rmax[mt][3], t[3]);
        }
      }
    }
    int t = nt*16 + r16;
    if (t < 22){
      #pragma unroll
      for (int mt = 0; mt < 4; mt++){
        float4 b4 = *(const float4*)(b0 + 16*mt + 4*q);
        shortx4 pk;
        pk[0] = (short)f2bf(fmaxf(rmax[mt][0] + b4.x, 0.f));
        pk[1] = (short)f2bf(fmaxf(rmax[mt][1] + b4.y, 0.f));
        pk[2] = (short)f2bf(fmaxf(rmax[mt][2] + b4.z, 0.f));
        pk[3] = (short)f2bf(fmaxf(rmax[mt][3] + b4.w, 0.f));
        *(shortx4*)(a0t + (t+2)*A0T_STR + 16*mt + 4*q) = pk;
      }
    }
  }

  // conv1 MFMA: C[64f][22p] = W[64f][320] * B[320][22p], k = kk*64 + c
  float4v acc[4][2];
  #pragma unroll
  for (int mt = 0; mt < 4; mt++)
    #pragma unroll
    for (int nt = 0; nt < 2; nt++)
      acc[mt][nt] = (float4v){0.f,0.f,0.f,0.f};
  #pragma unroll 1
  for (int ks = 0; ks < 10; ks++){
    int kk = ks >> 1;
    int cbase = (ks & 1)*32 + q*8;
    bf16x8 af[4];
    #pragma unroll
    for (int mt = 0; mt < 4; mt++)
      af[mt] = *(const bf16x8*)(w1b + (16*mt + r16)*320 + ks*32 + q*8);
    bf16x8 bv[2];
    #pragma unroll
    for (int nt = 0; nt < 2; nt++)
      bv[nt] = *(const bf16x8*)(a0t + (r16 + 16*nt + kk)*A0T_STR + cbase);
    #pragma unroll
    for (int mt = 0; mt < 4; mt++)
      #pragma unroll
      for (int nt = 0; nt < 2; nt++)
        acc[mt][nt] = __builtin_amdgcn_mfma_f32_16x16x32_bf16(af[mt], bv[nt], acc[mt][nt], 0, 0, 0);
  }

  u16* c1 = a0t;
  #pragma unroll
  for (int mt = 0; mt < 4; mt++){
    float4 bb = *(const float4*)(b1 + 16*mt + 4*q);
    #pragma unroll
    for (int reg = 0; reg < 4; reg++){
      int m = 16*mt + q*4 + reg;
      float bv_ = ((const float*)&bb)[reg];
      c1[m*C1_STR + r16] = f2bf(fmaxf(acc[mt][0][reg] + bv_, 0.f));
      if (r16 <= 4)
        c1[m*C1_STR + 16 + r16] = f2bf(fmaxf(acc[mt][1][reg] + bv_, 0.f));
    }
  }

  {
    bf16x8 f0 = *(const bf16x8*)(c1 + lane*C1_STR);
    bf16x8 f1 = *(const bf16x8*)(c1 + lane*C1_STR + 8);
    bf16x8 f2 = *(const bf16x8*)(c1 + lane*C1_STR + 16);
    float v[24];
    #pragma unroll
    for (int j = 0; j < 8; j++){
      v[j]    = bf2f((u16)f0[j]);
      v[8+j]  = bf2f((u16)f1[j]);
      v[16+j] = bf2f((u16)f2[j]);
    }
    #pragma unroll
    for (int t = 0; t < 3; t++){
      float m = v[t*7];
      #pragma unroll
      for (int r = 1; r < 7; r++) m = fmaxf(m, v[t*7+r]);
      a1k[lane*3 + t] = f2bf(m);
    }
  }

  float4v acc2[4];
  #pragma unroll
  for (int mt = 0; mt < 4; mt++) acc2[mt] = (float4v){0.f,0.f,0.f,0.f};
  #pragma unroll
  for (int ks = 0; ks < 6; ks++){
    bf16x8 bs = *(const bf16x8*)(a1k + ks*32 + q*8);
    #pragma unroll
    for (int mt = 0; mt < 4; mt++){
      bf16x8 af = *(const bf16x8*)(w2b + (16*mt + r16)*192 + ks*32 + q*8);
      acc2[mt] = __builtin_amdgcn_mfma_f32_16x16x32_bf16(af, bs, acc2[mt], 0, 0, 0);
    }
  }
  if (r16 == 0){
    #pragma unroll
    for (int mt = 0; mt < 4; mt++)
      #pragma unroll
      for (int reg = 0; reg < 4; reg++){
        int f = 16*mt + 4*q + reg;
        h0[(size_t)n*64 + f] = acc2[mt][reg] + b2[f];
      }
  }
}

// ---------------- bn stats partials, 64 blocks, layout [col][64] ------------
__global__ __launch_bounds__(256) void k_stats1(const float* __restrict__ h0, float* __restrict__ stat1p){
  int b = blockIdx.x, tid = threadIdx.x;
  int c4 = tid & 15, rg = tid >> 4;
  int r0 = b*122;
  float4v s = {0,0,0,0}, s2 = {0,0,0,0};
  #pragma unroll 1
  for (int t = 0; t < 7; t++){
    int r = r0 + rg + 16*t;
    float4v v = *(const float4v*)(h0 + (size_t)r*64 + c4*4);
    s += v; s2 += v*v;
  }
  if (rg < 10){
    int r = r0 + 112 + rg;
    float4v v = *(const float4v*)(h0 + (size_t)r*64 + c4*4);
    s += v; s2 += v*v;
  }
  __shared__ float red[16][128];
  #pragma unroll
  for (int cc = 0; cc < 4; cc++){
    red[rg][c4*4+cc] = s[cc];
    red[rg][64 + c4*4+cc] = s2[cc];
  }
  __syncthreads();
  if (tid < 128){
    float a = 0.f;
    #pragma unroll
    for (int r = 0; r < 16; r++) a += red[r][tid];
    if (tid < 64) stat1p[tid*64 + b] = a;
    else          stat1p[4096 + (tid-64)*64 + b] = a;
  }
}

__global__ __launch_bounds__(256) void k_stats2(const u16* __restrict__ hB, float* __restrict__ stat2p){
  int b = blockIdx.x, tid = threadIdx.x;
  int c4 = tid & 31, rg = tid >> 5;
  int r0 = b*122;
  float s[4] = {0,0,0,0}, s2[4] = {0,0,0,0};
  #pragma unroll 1
  for (int t = 0; t < 15; t++){
    int r = r0 + rg + 8*t;
    uint2 pv = *(const uint2*)(hB + (size_t)r*128 + c4*4);
    float v0 = bf2f(pv.x & 0xffffu), v1 = bf2f(pv.x >> 16);
    float v2 = bf2f(pv.y & 0xffffu), v3 = bf2f(pv.y >> 16);
    s[0]+=v0; s[1]+=v1; s[2]+=v2; s[3]+=v3;
    s2[0]+=v0*v0; s2[1]+=v1*v1; s2[2]+=v2*v2; s2[3]+=v3*v3;
  }
  if (rg < 2){
    int r = r0 + 120 + rg;
    uint2 pv = *(const uint2*)(hB + (size_t)r*128 + c4*4);
    float v0 = bf2f(pv.x & 0xffffu), v1 = bf2f(pv.x >> 16);
    float v2 = bf2f(pv.y & 0xffffu), v3 = bf2f(pv.y >> 16);
    s[0]+=v0; s[1]+=v1; s[2]+=v2; s[3]+=v3;
    s2[0]+=v0*v0; s2[1]+=v1*v1; s2[2]+=v2*v2; s2[3]+=v3*v3;
  }
  __shared__ float red[8][256];
  #pragma unroll
  for (int cc = 0; cc < 4; cc++){
    red[rg][c4*4+cc] = s[cc];
    red[rg][128 + c4*4+cc] = s2[cc];
  }
  __syncthreads();
  float a = 0.f;
  #pragma unroll
  for (int r = 0; r < 8; r++) a += red[r][tid];
  if (tid < 128) stat2p[tid*64 + b] = a;
  else           stat2p[8192 + (tid-128)*64 + b] = a;
}

// ---------------- fused 3-layer GNN via MFMA, 8 waves per graph -------------
#define HS_STR 136
#define HWT_STR 72
__global__ __launch_bounds__(512) void k_gnn(const float* __restrict__ h0,
    const float* __restrict__ stat1p,
    const float* __restrict__ bn1g, const float* __restrict__ bn1b,
    const u16* __restrict__ gwt0, const float* __restrict__ gb0,
    const u16* __restrict__ gwt1, const float* __restrict__ gb1,
    const u16* __restrict__ gwt2, const float* __restrict__ gb2,
    const u16* __restrict__ ewg_bf, u16* __restrict__ hB){
  int g = blockIdx.x, tid = threadIdx.x;
  int w = tid >> 6, lane = tid & 63, q = lane >> 4, r16 = lane & 15;
  int dt = w & 3, jh = w >> 2;
  __shared__ u16 hs[64*HS_STR];
  __shared__ u16 hwT[128*HWT_STR];
  __shared__ u16 ewl[64*EW_STR];
  __shared__ float bsc[64], bsh[64];

  bf16x8 af0[2], af1[4], af2[4];
  #pragma unroll
  for (int ks = 0; ks < 2; ks++)
    af0[ks] = *(const bf16x8*)(gwt0 + (16*w + r16)*64 + ks*32 + q*8);
  #pragma unroll
  for (int ks = 0; ks < 4; ks++)
    af1[ks] = *(const bf16x8*)(gwt1 + (16*w + r16)*128 + ks*32 + q*8);
  #pragma unroll
  for (int ks = 0; ks < 4; ks++)
    af2[ks] = *(const bf16x8*)(gwt2 + (16*w + r16)*128 + ks*32 + q*8);
  float4 b40 = *(const float4*)(gb0 + 16*w + 4*q);
  float4 b41 = *(const float4*)(gb1 + 16*w + 4*q);
  float4 b42 = *(const float4*)(gb2 + 16*w + 4*q);

  if (tid < 64){
    float4v sa = {0,0,0,0}, sb = {0,0,0,0};
    #pragma unroll
    for (int r = 0; r < 16; r++){
      sa += *(const float4v*)(stat1p + tid*64 + r*4);
      sb += *(const float4v*)(stat1p + 4096 + tid*64 + r*4);
    }
    float s = sa[0]+sa[1]+sa[2]+sa[3], s2 = sb[0]+sb[1]+sb[2]+sb[3];
    float m = s*(1.f/NNODES), v = s2*(1.f/NNODES) - m*m;
    float sc = rsqrtf(v + 1e-5f)*bn1g[tid];
    bsc[tid] = sc; bsh[tid] = bn1b[tid] - m*sc;
  }
  {
    const unsigned* src = (const unsigned*)ewg_bf + (size_t)g*(64*EW_STR/2);
    unsigned* dst = (unsigned*)ewl;
    for (int idx = tid; idx < 64*EW_STR/2; idx += 512) dst[idx] = src[idx];
  }
  {
    unsigned* hsd = (unsigned*)hs;
    for (int idx = tid; idx < 3*(HS_STR/2); idx += 512){
      int rr = 61 + idx/(HS_STR/2), cc = idx%(HS_STR/2);
      hsd[rr*(HS_STR/2) + cc] = 0;
    }
  }
  __syncthreads();
  {
    unsigned* hsd = (unsigned*)hs;
    for (int idx = tid; idx < 61*32; idx += 512){
      int i = idx >> 5, kw = idx & 31;
      float2 hv = *(const float2*)(h0 + ((size_t)g*61 + i)*64 + kw*2);
      int k0 = kw*2;
      float a = hv.x*bsc[k0] + bsh[k0];
      float b = hv.y*bsc[k0+1] + bsh[k0+1];
      hsd[i*(HS_STR/2) + kw] = (unsigned)f2bf(a) | ((unsigned)f2bf(b) << 16);
    }
  }
  bf16x8 ewf[2];
  #pragma unroll
  for (int ks = 0; ks < 2; ks++)
    ewf[ks] = *(const bf16x8*)(ewl + (16*dt + r16)*EW_STR + ks*32 + q*8);
  __syncthreads();

  // layer 0
  #pragma unroll
  for (int nt = 0; nt < 4; nt++){
    float4v acc = {b40.x, b40.y, b40.z, b40.w};
    #pragma unroll
    for (int ks = 0; ks < 2; ks++){
      bf16x8 bv = *(const bf16x8*)(hs + (nt*16 + r16)*HS_STR + ks*32 + q*8);
      acc = __builtin_amdgcn_mfma_f32_16x16x32_bf16(af0[ks], bv, acc, 0, 0, 0);
    }
    #pragma unroll
    for (int r = 0; r < 4; r++)
      hwT[(16*w + 4*q + r)*HWT_STR + nt*16 + r16] = f2bf(acc[r]);
  }
  __syncthreads();
  #pragma unroll
  for (int nt = 0; nt < 4; nt++){
    int j = (jh*4 + nt)*16;
    float4v acc = {0.f,0.f,0.f,0.f};
    #pragma unroll
    for (int ks = 0; ks < 2; ks++){
      bf16x8 bv = *(const bf16x8*)(hwT + (j + r16)*HWT_STR + ks*32 + q*8);
      acc = __builtin_amdgcn_mfma_f32_16x16x32_bf16(ewf[ks], bv, acc, 0, 0, 0);
    }
    #pragma unroll
    for (int r = 0; r < 4; r++){
      int d = 16*dt + 4*q + r;
      hs[d*HS_STR + j + r16] = f2bf(fmaxf(acc[r], 0.f));
    }
  }
  __syncthreads();

  // layer 1
  #pragma unroll
  for (int nt = 0; nt < 4; nt++){
    float4v acc = {b41.x, b41.y, b41.z, b41.w};
    #pragma unroll
    for (int ks = 0; ks < 4; ks++){
      bf16x8 bv = *(const bf16x8*)(hs + (nt*16 + r16)*HS_STR + ks*32 + q*8);
      acc = __builtin_amdgcn_mfma_f32_16x16x32_bf16(af1[ks], bv, acc, 0, 0, 0);
    }
    #pragma unroll
    for (int r = 0; r < 4; r++)
      hwT[(16*w + 4*q + r)*HWT_STR + nt*16 + r16] = f2bf(acc[r]);
  }
  __syncthreads();
  #pragma unroll
  for (int nt = 0; nt < 4; nt++){
    int j = (jh*4 + nt)*16;
    float4v acc = {0.f,0.f,0.f,0.f};
    #pragma unroll
    for (int ks = 0; ks < 2; ks++){
      bf16x8 bv = *(const bf16x8*)(hwT + (j + r16)*HWT_STR + ks*32 + q*8);
      acc = __builtin_amdgcn_mfma_f32_16x16x32_bf16(ewf[ks], bv, acc, 0, 0, 0);
    }
    #pragma unroll
    for (int r = 0; r < 4; r++){
      int d = 16*dt + 4*q + r;
      hs[d*HS_STR + j + r16] = f2bf(fmaxf(acc[r], 0.f));
    }
  }
  __syncthreads();

  // layer 2
  #pragma unroll
  for (int nt = 0; nt < 4; nt++){
    float4v acc = {b42.x, b42.y, b42.z, b42.w};
    #pragma unroll
    for (int ks = 0; ks < 4; ks++){
      bf16x8 bv = *(const bf16x8*)(hs + (nt*16 + r16)*HS_STR + ks*32 + q*8);
      acc = __builtin_amdgcn_mfma_f32_16x16x32_bf16(af2[ks], bv, acc, 0, 0, 0);
    }
    #pragma unroll
    for (int r = 0; r < 4; r++)
      hwT[(16*w + 4*q + r)*HWT_STR + nt*16 + r16] = f2bf(acc[r]);
  }
  __syncthreads();
  #pragma unroll
  for (int nt = 0; nt < 4; nt++){
    int j = (jh*4 + nt)*16;
    float4v acc = {0.f,0.f,0.f,0.f};
    #pragma unroll
    for (int ks = 0; ks < 2; ks++){
      bf16x8 bv = *(const bf16x8*)(hwT + (j + r16)*HWT_STR + ks*32 + q*8);
      acc = __builtin_amdgcn_mfma_f32_16x16x32_bf16(ewf[ks], bv, acc, 0, 0, 0);
    }
    #pragma unroll
    for (int r = 0; r < 4; r++){
      int d = 16*dt + 4*q + r;
      if (d < 61)
        hB[((size_t)g*61 + d)*128 + j + r16] = f2bf(acc[r]);
    }
  }
}

// ---------------- lin0 split-K via MFMA: block = (i, oh, gh), 244 blocks ----
#define AS_STR 136
__global__ __launch_bounds__(256) void k_mlp0(const u16* __restrict__ hB,
    const float* __restrict__ stat2p,
    const float* __restrict__ bn2g, const float* __restrict__ bn2b,
    const u16* __restrict__ lw0t, float* __restrict__ part){
  int bi = blockIdx.x; int i = bi >> 2, sub = bi & 3;
  int oh = sub & 1, gh = sub >> 1;
  int tid = threadIdx.x, w = tid >> 6, lane = tid & 63, q = lane >> 4, r16 = lane & 15;
  __shared__ u16 As[64*AS_STR];
  __shared__ float sc2[128], sh2[128];
  if (tid < 128){
    float4v sa = {0,0,0,0}, sb = {0,0,0,0};
    #pragma unroll
    for (int r = 0; r < 16; r++){
      sa += *(const float4v*)(stat2p + tid*64 + r*4);
      sb += *(const float4v*)(stat2p + 8192 + tid*64 + r*4);
    }
    float s = sa[0]+sa[1]+sa[2]+sa[3], s2 = sb[0]+sb[1]+sb[2]+sb[3];
    float m = s*(1.f/NNODES), v = s2*(1.f/NNODES) - m*m;
    float sc = rsqrtf(v + 1e-5f)*bn2g[tid];
    sc2[tid] = sc; sh2[tid] = bn2b[tid] - m*sc;
  }
  __syncthreads();
  {
    const unsigned* hbd = (const unsigned*)hB;
    unsigned* asd = (unsigned*)As;
    for (int idx = tid; idx < 4096; idx += 256){
      int gg = gh*64 + (idx >> 6), kw = idx & 63;
      unsigned pv = hbd[((size_t)gg*61 + i)*64 + kw];
      int k0 = kw*2;
      float a = bf2f(pv & 0xffffu)*sc2[k0] + sh2[k0];
      float b = bf2f(pv >> 16)*sc2[k0+1] + sh2[k0+1];
      asd[(idx >> 6)*(AS_STR/2) + kw] = (unsigned)f2bf(a) | ((unsigned)f2bf(b) << 16);
    }
  }
  __syncthreads();
  const u16* wbase = lw0t + ((size_t)i*128 + oh*64)*128;
  bf16x8 af[4];
  #pragma unroll
  for (int ks = 0; ks < 4; ks++)
    af[ks] = *(const bf16x8*)(As + (16*w + r16)*AS_STR + ks*32 + q*8);
  #pragma unroll 1
  for (int nt = 0; nt < 4; nt++){
    float4v acc = {0.f,0.f,0.f,0.f};
    #pragma unroll
    for (int ks = 0; ks < 4; ks++){
      bf16x8 bv = *(const bf16x8*)(wbase + (size_t)(nt*16 + r16)*128 + ks*32 + q*8);
      acc = __builtin_amdgcn_mfma_f32_16x16x32_bf16(af[ks], bv, acc, 0, 0, 0);
    }
    #pragma unroll
    for (int r = 0; r < 4; r++){
      int g = gh*64 + 16*w + 4*q + r;
      part[((size_t)g*61 + i)*128 + oh*64 + nt*16 + r16] = acc[r];
    }
  }
}

// ---------------- reduce partials + lin1 + lin2 + log_softmax, 512 thr ------
__global__ __launch_bounds__(512) void k_mlp1(const float* __restrict__ part,
    const float* __restrict__ lb0, const float* __restrict__ W1,
    const float* __restrict__ lb1, const float* __restrict__ W2,
    const float* __restrict__ lb2, float* __restrict__ out){
  int g = blockIdx.x, tid = threadIdx.x;
  int o = tid & 127, h = tid >> 7;   // h in 0..3
  __shared__ float red[512];
  __shared__ float y0[128], y1[128];
  float acc = 0.f;
  int i0 = h*16, cnt = (h == 3) ? 13 : 16;
  #pragma unroll 1
  for (int t = 0; t < cnt; t++)
    acc += part[((size_t)g*61 + i0 + t)*128 + o];
  red[tid] = acc;
  __syncthreads();
  if (tid < 128)
    y0[tid] = fmaxf(red[tid] + red[128+tid] + red[256+tid] + red[384+tid] + lb0[tid], 0.f);
  __syncthreads();
  float a = 0.f;
  #pragma unroll 1
  for (int t = 0; t < 32; t++){
    int k = h*32 + t;
    a += y0[k]*W1[k*128 + o];
  }
  red[tid] = a;
  __syncthreads();
  if (tid < 128)
    y1[tid] = fmaxf(red[tid] + red[128+tid] + red[256+tid] + red[384+tid] + lb1[tid], 0.f);
  __syncthreads();
  int k2 = tid >> 2, c2 = tid & 3;
  red[tid] = y1[k2]*W2[k2*4 + c2];
  __syncthreads();
  #pragma unroll
  for (int off = 256; off >= 4; off >>= 1){
    if (tid < off) red[tid] += red[tid + off];
    __syncthreads();
  }
  if (tid == 0){
    float v0 = red[0]+lb2[0], v1 = red[1]+lb2[1], v2 = red[2]+lb2[2], v3 = red[3]+lb2[3];
    float m = fmaxf(fmaxf(v0,v1), fmaxf(v2,v3));
    float lse = m + logf(expf(v0-m)+expf(v1-m)+expf(v2-m)+expf(v3-m));
    out[g*4+0]=v0-lse; out[g*4+1]=v1-lse; out[g*4+2]=v2-lse; out[g*4+3]=v3-lse;
  }
}

extern "C" void kernel_launch(void* const* d_in, const int* in_sizes, int n_in,
                              void* d_out, int out_size, void* d_ws, size_t ws_size,
                              hipStream_t stream){
  const float* x    = (const float*)d_in[0];
  const float* ef   = (const float*)d_in[3];
  const float* cw0  = (const float*)d_in[4];
  const float* cb0  = (const float*)d_in[5];
  const float* cw1  = (const float*)d_in[6];
  const float* cb1  = (const float*)d_in[7];
  const float* cw2  = (const float*)d_in[8];
  const float* cb2  = (const float*)d_in[9];
  const float* bn1g = (const float*)d_in[10];
  const float* bn1b = (const float*)d_in[11];
  const float* gw0  = (const float*)d_in[12];
  const float* gb0  = (const float*)d_in[13];
  const float* gw1  = (const float*)d_in[14];
  const float* gb1  = (const float*)d_in[15];
  const float* gw2  = (const float*)d_in[16];
  const float* gb2  = (const float*)d_in[17];
  const float* bn2g = (const float*)d_in[18];
  const float* bn2b = (const float*)d_in[19];
  const float* lw0  = (const float*)d_in[20];
  const float* lb0  = (const float*)d_in[21];
  const float* lw1  = (const float*)d_in[22];
  const float* lb1  = (const float*)d_in[23];
  const float* lw2  = (const float*)d_in[24];
  const float* lb2  = (const float*)d_in[25];
  const float* eww  = (const float*)d_in[26];
  const float* ewb  = (const float*)d_in[27];
  float* out = (float*)d_out;

  float* ws   = (float*)d_ws;
  float* w1s  = ws;               // 10240 f
  float* w2s  = w1s + 10240;      // 6144 f
  float* w0s  = w2s + 6144;       // 1024 f
  float* gws0 = w0s + 1024;       // 4096 f
  float* gws1 = gws0 + 4096;      // 8192 f
  float* gws2 = gws1 + 8192;      // 8192 f
  float* ew   = gws2 + 8192;      // 468480 f
  float* ewgs = ew + 468480;      // 294912 f
  float* h0   = ewgs + 294912;    // 499712 f
  float* hBs  = h0 + 499712;      // 499712 f
  float* s1p  = hBs + 499712;     // 8192 f
  float* s2p  = s1p + 8192;       // 16384 f
  float* part = s2p + 16384;      // 999424 f
  float* lw0s = part + 999424;    // 499712 f

  u16* w1b    = (u16*)w1s;
  u16* w2b    = (u16*)w2s;
  u16* w0p    = (u16*)w0s;
  u16* gwt0   = (u16*)gws0;
  u16* gwt1   = (u16*)gws1;
  u16* gwt2   = (u16*)gws2;
  u16* ewg_bf = (u16*)ewgs;
  u16* hB     = (u16*)hBs;
  u16* lw0t   = (u16*)lw0s;

  k_prep  <<<769, 256, 0, stream>>>(cw0, cw1, cw2, gw0, gw1, gw2, lw0, ef, eww, ewb,
                                    w0p, w1b, w2b, gwt0, gwt1, gwt2, lw0t, ew, out + 512);
  k_ewmat <<<NGRAPH, 256, 0, stream>>>(ew, ewg_bf);
  k_conv  <<<NNODES/4, 256, 0, stream>>>(x, w0p, cb0, w1b, cb1, w2b, cb2, h0);
  k_stats1<<<64, 256, 0, stream>>>(h0, s1p);
  k_gnn   <<<NGRAPH, 512, 0, stream>>>(h0, s1p, bn1g, bn1b,
                                       gwt0, gb0, gwt1, gb1, gwt2, gb2, ewg_bf, hB);
  k_stats2<<<64, 256, 0, stream>>>(hB, s2p);
  k_mlp0  <<<NPGN*4, 256, 0, stream>>>(hB, s2p, bn2g, bn2b, lw0t, part);
  k_mlp1  <<<NGRAPH, 512, 0, stream>>>(part, lb0, lw1, lb1, lw2, lb2, out);
}

// Round 9
// 255.225 us; speedup vs baseline: 1.0489x; 1.0489x over previous
//
#include <hip/hip_runtime.h>
#include <math.h>

#define NPGN 61
#define NGRAPH 128
#define NNODES (NPGN*NGRAPH)   // 7808
#define EPG 3660               // 61*60 edges per graph

typedef float float4v __attribute__((ext_vector_type(4)));
typedef short bf16x8 __attribute__((ext_vector_type(8)));
typedef short shortx4 __attribute__((ext_vector_type(4)));
typedef unsigned short u16;

__device__ __forceinline__ u16 f2bf(float v){
  union { float f; unsigned u; } x; x.f = v;
  unsigned r = (x.u + 0x7FFFu + ((x.u >> 16) & 1u)) >> 16;
  return (u16)r;
}
__device__ __forceinline__ float bf2f(unsigned u){
  union { unsigned u; float f; } x; x.u = u << 16;
  return x.f;
}

// ---------------- fused prep: weight re-layouts + lw0 transpose -------------
// blocks [0,296): w-layouts ; [296,540): lw0t
__global__ __launch_bounds__(256) void k_prep(const float* __restrict__ w0,
    const float* __restrict__ w1, const float* __restrict__ w2,
    const float* __restrict__ gw0, const float* __restrict__ gw1, const float* __restrict__ gw2,
    const float* __restrict__ lw0,
    u16* __restrict__ w0p, u16* __restrict__ w1b, u16* __restrict__ w2b,
    u16* __restrict__ gwt0, u16* __restrict__ gwt1, u16* __restrict__ gwt2,
    u16* __restrict__ lw0t){
  __shared__ __align__(16) u16 tile[32*132];
  int b = blockIdx.x, tid = threadIdx.x;
  if (b < 296){
    int idx = b*256 + tid;
    if (idx < 20480){
      int f = idx / 320, r = idx - f*320;
      int kk = r >> 6, c = r & 63;
      w1b[idx] = f2bf(w1[f*320 + c*5 + kk]);
    } else if (idx < 32768){
      int j = idx - 20480; w2b[j] = f2bf(w2[j]);
    } else if (idx < 40960){
      int j = idx - 32768; int jj = j >> 6, k = j & 63; gwt0[j] = f2bf(gw0[k*128 + jj]);
    } else if (idx < 57344){
      int j = idx - 40960; int jj = j >> 7, k = j & 127; gwt1[j] = f2bf(gw1[k*128 + jj]);
    } else if (idx < 73728){
      int j = idx - 57344; int jj = j >> 7, k = j & 127; gwt2[j] = f2bf(gw2[k*128 + jj]);
    } else if (idx < 75776){
      int j = idx - 73728; int f = j >> 5, k = j & 31;
      w0p[j] = (k < 7) ? f2bf(w0[f*7 + k]) : (u16)0;
    }
  } else {
    int bb = b - 296;
    int i = bb >> 2, oq = bb & 3;      // o-chunk of 32
    for (int idx = tid; idx < 4096; idx += 256){
      int k = idx >> 5, ol = idx & 31;
      tile[ol*132 + k] = f2bf(lw0[((size_t)i*128 + k)*128 + oq*32 + ol]);
    }
    __syncthreads();
    unsigned* dst = (unsigned*)lw0t;
    for (int idx = tid; idx < 2048; idx += 256){
      int ol = idx >> 6, kw = idx & 63;
      unsigned v = (unsigned)tile[ol*132 + 2*kw] | ((unsigned)tile[ol*132 + 2*kw + 1] << 16);
      dst[((size_t)i*128 + oq*32 + ol)*64 + kw] = v;
    }
  }
}

// ---------------- edge tanh + dense per-graph matrix + transposed output ----
#define EW_STR 72
__global__ __launch_bounds__(256) void k_ewmat(const float* __restrict__ ef,
    const float* __restrict__ eww, const float* __restrict__ ewb,
    u16* __restrict__ ewg_bf, float* __restrict__ out2){
  int g = blockIdx.x, tid = threadIdx.x;
  __shared__ u16 t[64*EW_STR];
  unsigned* td = (unsigned*)t;
  for (int idx = tid; idx < 64*EW_STR/2; idx += 256) td[idx] = 0;
  __syncthreads();
  float v0 = eww[0], v1 = eww[1], v2 = eww[2], bb = ewb[0];
  const float* efg = ef + (size_t)g*EPG*3;
  for (int idx = tid; idx < EPG; idx += 256){
    const float* p = efg + idx*3;
    float v = tanhf(p[0]*v0 + p[1]*v1 + p[2]*v2 + bb);
    int s = idx/60, r = idx - s*60;
    int d = r + (r >= s ? 1 : 0);
    t[d*EW_STR + s] = f2bf(v);
    out2[(size_t)idx*128 + g] = v;
  }
  __syncthreads();
  unsigned* dst = (unsigned*)ewg_bf + (size_t)g*(64*EW_STR/2);
  for (int idx = tid; idx < 64*EW_STR/2; idx += 256) dst[idx] = td[idx];
}

// ---------------- conv0: one wave per node, MFMA pool-aligned, -> a0g -------
#define XSH_STR 256  // u16 per shifted copy
__global__ __launch_bounds__(256) void k_conv0(const float* __restrict__ x,
    const u16* __restrict__ w0p, const float* __restrict__ b0,
    u16* __restrict__ a0g){
  int w = threadIdx.x >> 6, lane = threadIdx.x & 63;
  int n = blockIdx.x*4 + w;
  int q = lane >> 4, r16 = lane & 15;
  __shared__ __align__(16) u16 xsh_s[4][4*XSH_STR];   // 2 KB/wave
  u16* xsh = xsh_s[w];

  {
    unsigned* xz = (unsigned*)xsh;
    #pragma unroll
    for (int t = 0; t < 8; t++) xz[lane + 64*t] = 0;
  }
  const float* xrow = x + (size_t)n*160;
  if (lane < 40){
    float4 f0 = *(const float4*)(xrow + 4*lane);
    float e4 = 0.f, e5 = 0.f, e6 = 0.f;
    if (lane < 39){ e4 = xrow[4*lane+4]; e5 = xrow[4*lane+5]; e6 = xrow[4*lane+6]; }
    u16 xb[7];
    xb[0]=f2bf(f0.x); xb[1]=f2bf(f0.y); xb[2]=f2bf(f0.z); xb[3]=f2bf(f0.w);
    xb[4]=f2bf(e4);   xb[5]=f2bf(e5);   xb[6]=f2bf(e6);
    #pragma unroll
    for (int b = 0; b < 4; b++){
      unsigned* dst = (unsigned*)(xsh + b*XSH_STR);
      dst[2*lane]   = (unsigned)xb[b]   | ((unsigned)xb[b+1] << 16);
      dst[2*lane+1] = (unsigned)xb[b+2] | ((unsigned)xb[b+3] << 16);
    }
  }

  bf16x8 a0f[4];
  #pragma unroll
  for (int mt = 0; mt < 4; mt++)
    a0f[mt] = *(const bf16x8*)(w0p + (16*mt + r16)*32 + q*8);

  #pragma unroll
  for (int nt = 0; nt < 2; nt++){
    float4v rmax[4];
    #pragma unroll
    for (int r = 0; r < 7; r++){
      int o = 112*nt + 7*r16 + r + 8*q;
      int bsh = o & 3, idx = o - bsh;
      const u16* base = xsh + bsh*XSH_STR + idx;
      shortx4 lo = *(const shortx4*)(base);
      shortx4 hi = *(const shortx4*)(base + 4);
      bf16x8 bb;
      bb[0]=lo[0]; bb[1]=lo[1]; bb[2]=lo[2]; bb[3]=lo[3];
      bb[4]=hi[0]; bb[5]=hi[1]; bb[6]=hi[2]; bb[7]=hi[3];
      #pragma unroll
      for (int mt = 0; mt < 4; mt++){
        float4v t = __builtin_amdgcn_mfma_f32_16x16x32_bf16(a0f[mt], bb,
                        (float4v){0.f,0.f,0.f,0.f}, 0, 0, 0);
        if (r == 0) rmax[mt] = t;
        else {
          rmax[mt][0] = fmaxf(rmax[mt][0], t[0]);
          rmax[mt][1] = fmaxf(rmax[mt][1], t[1]);
          rmax[mt][2] = fmaxf(rmax[mt][2], t[2]);
          rmax[mt][3] = fmaxf(rmax[mt][3], t[3]);
        }
      }
    }
    int t = nt*16 + r16;
    if (t < 22){
      u16* dst = a0g + (size_t)n*1408 + t*64;
      #pragma unroll
      for (int mt = 0; mt < 4; mt++){
        float4 b4 = *(const float4*)(b0 + 16*mt + 4*q);
        shortx4 pk;
        pk[0] = (short)f2bf(fmaxf(rmax[mt][0] + b4.x, 0.f));
        pk[1] = (short)f2bf(fmaxf(rmax[mt][1] + b4.y, 0.f));
        pk[2] = (short)f2bf(fmaxf(rmax[mt][2] + b4.z, 0.f));
        pk[3] = (short)f2bf(fmaxf(rmax[mt][3] + b4.w, 0.f));
        *(shortx4*)(dst + 16*mt + 4*q) = pk;
      }
    }
  }
}

// ---------------- conv1+pool+conv2: one wave per node -----------------------
#define A0T_STR 72   // u16 units (144 B)
#define C1_STR 40    // u16 units (80 B)
__global__ __launch_bounds__(256) void k_conv12(const u16* __restrict__ a0g,
    const u16* __restrict__ w1b, const float* __restrict__ b1,
    const u16* __restrict__ w2b, const float* __restrict__ b2,
    float* __restrict__ h0){
  int w = threadIdx.x >> 6, lane = threadIdx.x & 63;
  int n = blockIdx.x*4 + w;
  int q = lane >> 4, r16 = lane & 15;
  __shared__ __align__(16) u16 a0t_s[4][36*A0T_STR];  // 5184 B/wave; c1 overlays
  __shared__ __align__(16) u16 a1k_s[4][208];
  u16* a0t = a0t_s[w];
  u16* a1k = a1k_s[w];

  // zero pad rows 0,1 and 24..35 (504 u32)
  {
    unsigned* z = (unsigned*)a0t;
    #pragma unroll
    for (int t = 0; t < 8; t++){
      int idx = t*64 + lane;
      if (idx < 504){
        int flat = idx + (idx >= 72 ? 792 : 0);
        z[flat] = 0;
      }
    }
  }
  // stage rows 2..23 from a0g[n] (176 uint4)
  {
    const uint4* src = (const uint4*)(a0g + (size_t)n*1408);
    #pragma unroll
    for (int t = 0; t < 3; t++){
      int idx = t*64 + lane;
      if (idx < 176){
        int row = (idx >> 3) + 2, cp4 = idx & 7;
        *(uint4*)(a0t + row*A0T_STR + cp4*8) = src[idx];
      }
    }
  }

  // conv1 MFMA: C[64f][22p] = W[64f][320] * B[320][22p], k = kk*64 + c
  float4v acc[4][2];
  #pragma unroll
  for (int mt = 0; mt < 4; mt++)
    #pragma unroll
    for (int nt = 0; nt < 2; nt++)
      acc[mt][nt] = (float4v){0.f,0.f,0.f,0.f};
  #pragma unroll 1
  for (int ks = 0; ks < 10; ks++){
    int kk = ks >> 1;
    int cbase = (ks & 1)*32 + q*8;
    bf16x8 af[4];
    #pragma unroll
    for (int mt = 0; mt < 4; mt++)
      af[mt] = *(const bf16x8*)(w1b + (16*mt + r16)*320 + ks*32 + q*8);
    bf16x8 bv[2];
    #pragma unroll
    for (int nt = 0; nt < 2; nt++)
      bv[nt] = *(const bf16x8*)(a0t + (r16 + 16*nt + kk)*A0T_STR + cbase);
    #pragma unroll
    for (int mt = 0; mt < 4; mt++)
      #pragma unroll
      for (int nt = 0; nt < 2; nt++)
        acc[mt][nt] = __builtin_amdgcn_mfma_f32_16x16x32_bf16(af[mt], bv[nt], acc[mt][nt], 0, 0, 0);
  }

  // bias + relu -> c1 (bf16, overlays a0t; same-wave DS ops in-order)
  u16* c1 = a0t;
  #pragma unroll
  for (int mt = 0; mt < 4; mt++){
    float4 bb = *(const float4*)(b1 + 16*mt + 4*q);
    #pragma unroll
    for (int reg = 0; reg < 4; reg++){
      int m = 16*mt + q*4 + reg;
      float bv_ = ((const float*)&bb)[reg];
      c1[m*C1_STR + r16] = f2bf(fmaxf(acc[mt][0][reg] + bv_, 0.f));
      if (r16 <= 4)
        c1[m*C1_STR + 16 + r16] = f2bf(fmaxf(acc[mt][1][reg] + bv_, 0.f));
    }
  }

  // maxpool7 (21 -> 3), lane = channel; a1k[c*3+t]
  {
    bf16x8 f0 = *(const bf16x8*)(c1 + lane*C1_STR);
    bf16x8 f1 = *(const bf16x8*)(c1 + lane*C1_STR + 8);
    bf16x8 f2 = *(const bf16x8*)(c1 + lane*C1_STR + 16);
    float v[24];
    #pragma unroll
    for (int j = 0; j < 8; j++){
      v[j]    = bf2f((u16)f0[j]);
      v[8+j]  = bf2f((u16)f1[j]);
      v[16+j] = bf2f((u16)f2[j]);
    }
    #pragma unroll
    for (int t = 0; t < 3; t++){
      float m = v[t*7];
      #pragma unroll
      for (int r = 1; r < 7; r++) m = fmaxf(m, v[t*7+r]);
      a1k[lane*3 + t] = f2bf(m);
    }
  }

  // conv2 via MFMA: C[f][*] = W2[64f][192k] * a1[192k]
  float4v acc2[4];
  #pragma unroll
  for (int mt = 0; mt < 4; mt++) acc2[mt] = (float4v){0.f,0.f,0.f,0.f};
  #pragma unroll
  for (int ks = 0; ks < 6; ks++){
    bf16x8 bs = *(const bf16x8*)(a1k + ks*32 + q*8);
    #pragma unroll
    for (int mt = 0; mt < 4; mt++){
      bf16x8 af = *(const bf16x8*)(w2b + (16*mt + r16)*192 + ks*32 + q*8);
      acc2[mt] = __builtin_amdgcn_mfma_f32_16x16x32_bf16(af, bs, acc2[mt], 0, 0, 0);
    }
  }
  if (r16 == 0){
    #pragma unroll
    for (int mt = 0; mt < 4; mt++)
      #pragma unroll
      for (int reg = 0; reg < 4; reg++){
        int f = 16*mt + 4*q + reg;
        h0[(size_t)n*64 + f] = acc2[mt][reg] + b2[f];
      }
  }
}

// ---------------- bn stats partials, 64 blocks, layout [col][64] ------------
__global__ __launch_bounds__(256) void k_stats1(const float* __restrict__ h0, float* __restrict__ stat1p){
  int b = blockIdx.x, tid = threadIdx.x;
  int c4 = tid & 15, rg = tid >> 4;
  int r0 = b*122;
  float4v s = {0,0,0,0}, s2 = {0,0,0,0};
  #pragma unroll 1
  for (int t = 0; t < 7; t++){
    int r = r0 + rg + 16*t;
    float4v v = *(const float4v*)(h0 + (size_t)r*64 + c4*4);
    s += v; s2 += v*v;
  }
  if (rg < 10){
    int r = r0 + 112 + rg;
    float4v v = *(const float4v*)(h0 + (size_t)r*64 + c4*4);
    s += v; s2 += v*v;
  }
  __shared__ float red[16][128];
  #pragma unroll
  for (int cc = 0; cc < 4; cc++){
    red[rg][c4*4+cc] = s[cc];
    red[rg][64 + c4*4+cc] = s2[cc];
  }
  __syncthreads();
  if (tid < 128){
    float a = 0.f;
    #pragma unroll
    for (int r = 0; r < 16; r++) a += red[r][tid];
    if (tid < 64) stat1p[tid*64 + b] = a;
    else          stat1p[4096 + (tid-64)*64 + b] = a;
  }
}

__global__ __launch_bounds__(256) void k_stats2(const u16* __restrict__ hB, float* __restrict__ stat2p){
  int b = blockIdx.x, tid = threadIdx.x;
  int c4 = tid & 31, rg = tid >> 5;
  int r0 = b*122;
  float s[4] = {0,0,0,0}, s2[4] = {0,0,0,0};
  #pragma unroll 1
  for (int t = 0; t < 15; t++){
    int r = r0 + rg + 8*t;
    uint2 pv = *(const uint2*)(hB + (size_t)r*128 + c4*4);
    float v0 = bf2f(pv.x & 0xffffu), v1 = bf2f(pv.x >> 16);
    float v2 = bf2f(pv.y & 0xffffu), v3 = bf2f(pv.y >> 16);
    s[0]+=v0; s[1]+=v1; s[2]+=v2; s[3]+=v3;
    s2[0]+=v0*v0; s2[1]+=v1*v1; s2[2]+=v2*v2; s2[3]+=v3*v3;
  }
  if (rg < 2){
    int r = r0 + 120 + rg;
    uint2 pv = *(const uint2*)(hB + (size_t)r*128 + c4*4);
    float v0 = bf2f(pv.x & 0xffffu), v1 = bf2f(pv.x >> 16);
    float v2 = bf2f(pv.y & 0xffffu), v3 = bf2f(pv.y >> 16);
    s[0]+=v0; s[1]+=v1; s[2]+=v2; s[3]+=v3;
    s2[0]+=v0*v0; s2[1]+=v1*v1; s2[2]+=v2*v2; s2[3]+=v3*v3;
  }
  __shared__ float red[8][256];
  #pragma unroll
  for (int cc = 0; cc < 4; cc++){
    red[rg][c4*4+cc] = s[cc];
    red[rg][128 + c4*4+cc] = s2[cc];
  }
  __syncthreads();
  float a = 0.f;
  #pragma unroll
  for (int r = 0; r < 8; r++) a += red[r][tid];
  if (tid < 128) stat2p[tid*64 + b] = a;
  else           stat2p[8192 + (tid-128)*64 + b] = a;
}

// ---------------- fused 3-layer GNN via MFMA, 8 waves per graph -------------
#define HS_STR 136
#define HWT_STR 72
__global__ __launch_bounds__(512) void k_gnn(const float* __restrict__ h0,
    const float* __restrict__ stat1p,
    const float* __restrict__ bn1g, const float* __restrict__ bn1b,
    const u16* __restrict__ gwt0, const float* __restrict__ gb0,
    const u16* __restrict__ gwt1, const float* __restrict__ gb1,
    const u16* __restrict__ gwt2, const float* __restrict__ gb2,
    const u16* __restrict__ ewg_bf, u16* __restrict__ hB){
  int g = blockIdx.x, tid = threadIdx.x;
  int w = tid >> 6, lane = tid & 63, q = lane >> 4, r16 = lane & 15;
  int dt = w & 3, jh = w >> 2;
  __shared__ u16 hs[64*HS_STR];
  __shared__ u16 hwT[128*HWT_STR];
  __shared__ u16 ewl[64*EW_STR];
  __shared__ float bsc[64], bsh[64];

  bf16x8 af0[2], af1[4], af2[4];
  #pragma unroll
  for (int ks = 0; ks < 2; ks++)
    af0[ks] = *(const bf16x8*)(gwt0 + (16*w + r16)*64 + ks*32 + q*8);
  #pragma unroll
  for (int ks = 0; ks < 4; ks++)
    af1[ks] = *(const bf16x8*)(gwt1 + (16*w + r16)*128 + ks*32 + q*8);
  #pragma unroll
  for (int ks = 0; ks < 4; ks++)
    af2[ks] = *(const bf16x8*)(gwt2 + (16*w + r16)*128 + ks*32 + q*8);
  float4 b40 = *(const float4*)(gb0 + 16*w + 4*q);
  float4 b41 = *(const float4*)(gb1 + 16*w + 4*q);
  float4 b42 = *(const float4*)(gb2 + 16*w + 4*q);

  if (tid < 64){
    float4v sa = {0,0,0,0}, sb = {0,0,0,0};
    #pragma unroll
    for (int r = 0; r < 16; r++){
      sa += *(const float4v*)(stat1p + tid*64 + r*4);
      sb += *(const float4v*)(stat1p + 4096 + tid*64 + r*4);
    }
    float s = sa[0]+sa[1]+sa[2]+sa[3], s2 = sb[0]+sb[1]+sb[2]+sb[3];
    float m = s*(1.f/NNODES), v = s2*(1.f/NNODES) - m*m;
    float sc = rsqrtf(v + 1e-5f)*bn1g[tid];
    bsc[tid] = sc; bsh[tid] = bn1b[tid] - m*sc;
  }
  {
    const unsigned* src = (const unsigned*)ewg_bf + (size_t)g*(64*EW_STR/2);
    unsigned* dst = (unsigned*)ewl;
    for (int idx = tid; idx < 64*EW_STR/2; idx += 512) dst[idx] = src[idx];
  }
  {
    unsigned* hsd = (unsigned*)hs;
    for (int idx = tid; idx < 3*(HS_STR/2); idx += 512){
      int rr = 61 + idx/(HS_STR/2), cc = idx%(HS_STR/2);
      hsd[rr*(HS_STR/2) + cc] = 0;
    }
  }
  __syncthreads();
  {
    unsigned* hsd = (unsigned*)hs;
    for (int idx = tid; idx < 61*32; idx += 512){
      int i = idx >> 5, kw = idx & 31;
      float2 hv = *(const float2*)(h0 + ((size_t)g*61 + i)*64 + kw*2);
      int k0 = kw*2;
      float a = hv.x*bsc[k0] + bsh[k0];
      float b = hv.y*bsc[k0+1] + bsh[k0+1];
      hsd[i*(HS_STR/2) + kw] = (unsigned)f2bf(a) | ((unsigned)f2bf(b) << 16);
    }
  }
  bf16x8 ewf[2];
  #pragma unroll
  for (int ks = 0; ks < 2; ks++)
    ewf[ks] = *(const bf16x8*)(ewl + (16*dt + r16)*EW_STR + ks*32 + q*8);
  __syncthreads();

  // layer 0
  #pragma unroll
  for (int nt = 0; nt < 4; nt++){
    float4v acc = {b40.x, b40.y, b40.z, b40.w};
    #pragma unroll
    for (int ks = 0; ks < 2; ks++){
      bf16x8 bv = *(const bf16x8*)(hs + (nt*16 + r16)*HS_STR + ks*32 + q*8);
      acc = __builtin_amdgcn_mfma_f32_16x16x32_bf16(af0[ks], bv, acc, 0, 0, 0);
    }
    #pragma unroll
    for (int r = 0; r < 4; r++)
      hwT[(16*w + 4*q + r)*HWT_STR + nt*16 + r16] = f2bf(acc[r]);
  }
  __syncthreads();
  #pragma unroll
  for (int nt = 0; nt < 4; nt++){
    int j = (jh*4 + nt)*16;
    float4v acc = {0.f,0.f,0.f,0.f};
    #pragma unroll
    for (int ks = 0; ks < 2; ks++){
      bf16x8 bv = *(const bf16x8*)(hwT + (j + r16)*HWT_STR + ks*32 + q*8);
      acc = __builtin_amdgcn_mfma_f32_16x16x32_bf16(ewf[ks], bv, acc, 0, 0, 0);
    }
    #pragma unroll
    for (int r = 0; r < 4; r++){
      int d = 16*dt + 4*q + r;
      hs[d*HS_STR + j + r16] = f2bf(fmaxf(acc[r], 0.f));
    }
  }
  __syncthreads();

  // layer 1
  #pragma unroll
  for (int nt = 0; nt < 4; nt++){
    float4v acc = {b41.x, b41.y, b41.z, b41.w};
    #pragma unroll
    for (int ks = 0; ks < 4; ks++){
      bf16x8 bv = *(const bf16x8*)(hs + (nt*16 + r16)*HS_STR + ks*32 + q*8);
      acc = __builtin_amdgcn_mfma_f32_16x16x32_bf16(af1[ks], bv, acc, 0, 0, 0);
    }
    #pragma unroll
    for (int r = 0; r < 4; r++)
      hwT[(16*w + 4*q + r)*HWT_STR + nt*16 + r16] = f2bf(acc[r]);
  }
  __syncthreads();
  #pragma unroll
  for (int nt = 0; nt < 4; nt++){
    int j = (jh*4 + nt)*16;
    float4v acc = {0.f,0.f,0.f,0.f};
    #pragma unroll
    for (int ks = 0; ks < 2; ks++){
      bf16x8 bv = *(const bf16x8*)(hwT + (j + r16)*HWT_STR + ks*32 + q*8);
      acc = __builtin_amdgcn_mfma_f32_16x16x32_bf16(ewf[ks], bv, acc, 0, 0, 0);
    }
    #pragma unroll
    for (int r = 0; r < 4; r++){
      int d = 16*dt + 4*q + r;
      hs[d*HS_STR + j + r16] = f2bf(fmaxf(acc[r], 0.f));
    }
  }
  __syncthreads();

  // layer 2
  #pragma unroll
  for (int nt = 0; nt < 4; nt++){
    float4v acc = {b42.x, b42.y, b42.z, b42.w};
    #pragma unroll
    for (int ks = 0; ks < 4; ks++){
      bf16x8 bv = *(const bf16x8*)(hs + (nt*16 + r16)*HS_STR + ks*32 + q*8);
      acc = __builtin_amdgcn_mfma_f32_16x16x32_bf16(af2[ks], bv, acc, 0, 0, 0);
    }
    #pragma unroll
    for (int r = 0; r < 4; r++)
      hwT[(16*w + 4*q + r)*HWT_STR + nt*16 + r16] = f2bf(acc[r]);
  }
  __syncthreads();
  #pragma unroll
  for (int nt = 0; nt < 4; nt++){
    int j = (jh*4 + nt)*16;
    float4v acc = {0.f,0.f,0.f,0.f};
    #pragma unroll
    for (int ks = 0; ks < 2; ks++){
      bf16x8 bv = *(const bf16x8*)(hwT + (j + r16)*HWT_STR + ks*32 + q*8);
      acc = __builtin_amdgcn_mfma_f32_16x16x32_bf16(ewf[ks], bv, acc, 0, 0, 0);
    }
    #pragma unroll
    for (int r = 0; r < 4; r++){
      int d = 16*dt + 4*q + r;
      if (d < 61)
        hB[((size_t)g*61 + d)*128 + j + r16] = f2bf(acc[r]);
    }
  }
}

// ---------------- lin0 split-K via MFMA: block = (i, oh, gh), 244 blocks ----
#define AS_STR 136
__global__ __launch_bounds__(256) void k_mlp0(const u16* __restrict__ hB,
    const float* __restrict__ stat2p,
    const float* __restrict__ bn2g, const float* __restrict__ bn2b,
    const u16* __restrict__ lw0t, float* __restrict__ part){
  int bi = blockIdx.x; int i = bi >> 2, sub = bi & 3;
  int oh = sub & 1, gh = sub >> 1;
  int tid = threadIdx.x, w = tid >> 6, lane = tid & 63, q = lane >> 4, r16 = lane & 15;
  __shared__ u16 As[64*AS_STR];
  __shared__ float sc2[128], sh2[128];
  if (tid < 128){
    float4v sa = {0,0,0,0}, sb = {0,0,0,0};
    #pragma unroll
    for (int r = 0; r < 16; r++){
      sa += *(const float4v*)(stat2p + tid*64 + r*4);
      sb += *(const float4v*)(stat2p + 8192 + tid*64 + r*4);
    }
    float s = sa[0]+sa[1]+sa[2]+sa[3], s2 = sb[0]+sb[1]+sb[2]+sb[3];
    float m = s*(1.f/NNODES), v = s2*(1.f/NNODES) - m*m;
    float sc = rsqrtf(v + 1e-5f)*bn2g[tid];
    sc2[tid] = sc; sh2[tid] = bn2b[tid] - m*sc;
  }
  __syncthreads();
  {
    const unsigned* hbd = (const unsigned*)hB;
    unsigned* asd = (unsigned*)As;
    for (int idx = tid; idx < 4096; idx += 256){
      int gg = gh*64 + (idx >> 6), kw = idx & 63;
      unsigned pv = hbd[((size_t)gg*61 + i)*64 + kw];
      int k0 = kw*2;
      float a = bf2f(pv & 0xffffu)*sc2[k0] + sh2[k0];
      float b = bf2f(pv >> 16)*sc2[k0+1] + sh2[k0+1];
      asd[(idx >> 6)*(AS_STR/2) + kw] = (unsigned)f2bf(a) | ((unsigned)f2bf(b) << 16);
    }
  }
  __syncthreads();
  const u16* wbase = lw0t + ((size_t)i*128 + oh*64)*128;
  bf16x8 af[4];
  #pragma unroll
  for (int ks = 0; ks < 4; ks++)
    af[ks] = *(const bf16x8*)(As + (16*w + r16)*AS_STR + ks*32 + q*8);
  #pragma unroll 1
  for (int nt = 0; nt < 4; nt++){
    float4v acc = {0.f,0.f,0.f,0.f};
    #pragma unroll
    for (int ks = 0; ks < 4; ks++){
      bf16x8 bv = *(const bf16x8*)(wbase + (size_t)(nt*16 + r16)*128 + ks*32 + q*8);
      acc = __builtin_amdgcn_mfma_f32_16x16x32_bf16(af[ks], bv, acc, 0, 0, 0);
    }
    #pragma unroll
    for (int r = 0; r < 4; r++){
      int g = gh*64 + 16*w + 4*q + r;
      part[((size_t)g*61 + i)*128 + oh*64 + nt*16 + r16] = acc[r];
    }
  }
}

// ---------------- reduce partials + lin1 + lin2 + log_softmax, 512 thr ------
__global__ __launch_bounds__(512) void k_mlp1(const float* __restrict__ part,
    const float* __restrict__ lb0, const float* __restrict__ W1,
    const float* __restrict__ lb1, const float* __restrict__ W2,
    const float* __restrict__ lb2, float* __restrict__ out){
  int g = blockIdx.x, tid = threadIdx.x;
  int o = tid & 127, h = tid >> 7;   // h in 0..3
  __shared__ float red[512];
  __shared__ float y0[128], y1[128];
  float acc = 0.f;
  int i0 = h*16, cnt = (h == 3) ? 13 : 16;
  #pragma unroll 1
  for (int t = 0; t < cnt; t++)
    acc += part[((size_t)g*61 + i0 + t)*128 + o];
  red[tid] = acc;
  __syncthreads();
  if (tid < 128)
    y0[tid] = fmaxf(red[tid] + red[128+tid] + red[256+tid] + red[384+tid] + lb0[tid], 0.f);
  __syncthreads();
  float a = 0.f;
  #pragma unroll 1
  for (int t = 0; t < 32; t++){
    int k = h*32 + t;
    a += y0[k]*W1[k*128 + o];
  }
  red[tid] = a;
  __syncthreads();
  if (tid < 128)
    y1[tid] = fmaxf(red[tid] + red[128+tid] + red[256+tid] + red[384+tid] + lb1[tid], 0.f);
  __syncthreads();
  int k2 = tid >> 2, c2 = tid & 3;
  red[tid] = y1[k2]*W2[k2*4 + c2];
  __syncthreads();
  #pragma unroll
  for (int off = 256; off >= 4; off >>= 1){
    if (tid < off) red[tid] += red[tid + off];
    __syncthreads();
  }
  if (tid == 0){
    float v0 = red[0]+lb2[0], v1 = red[1]+lb2[1], v2 = red[2]+lb2[2], v3 = red[3]+lb2[3];
    float m = fmaxf(fmaxf(v0,v1), fmaxf(v2,v3));
    float lse = m + logf(expf(v0-m)+expf(v1-m)+expf(v2-m)+expf(v3-m));
    out[g*4+0]=v0-lse; out[g*4+1]=v1-lse; out[g*4+2]=v2-lse; out[g*4+3]=v3-lse;
  }
}

extern "C" void kernel_launch(void* const* d_in, const int* in_sizes, int n_in,
                              void* d_out, int out_size, void* d_ws, size_t ws_size,
                              hipStream_t stream){
  const float* x    = (const float*)d_in[0];
  const float* ef   = (const float*)d_in[3];
  const float* cw0  = (const float*)d_in[4];
  const float* cb0  = (const float*)d_in[5];
  const float* cw1  = (const float*)d_in[6];
  const float* cb1  = (const float*)d_in[7];
  const float* cw2  = (const float*)d_in[8];
  const float* cb2  = (const float*)d_in[9];
  const float* bn1g = (const float*)d_in[10];
  const float* bn1b = (const float*)d_in[11];
  const float* gw0  = (const float*)d_in[12];
  const float* gb0  = (const float*)d_in[13];
  const float* gw1  = (const float*)d_in[14];
  const float* gb1  = (const float*)d_in[15];
  const float* gw2  = (const float*)d_in[16];
  const float* gb2  = (const float*)d_in[17];
  const float* bn2g = (const float*)d_in[18];
  const float* bn2b = (const float*)d_in[19];
  const float* lw0  = (const float*)d_in[20];
  const float* lb0  = (const float*)d_in[21];
  const float* lw1  = (const float*)d_in[22];
  const float* lb1  = (const float*)d_in[23];
  const float* lw2  = (const float*)d_in[24];
  const float* lb2  = (const float*)d_in[25];
  const float* eww  = (const float*)d_in[26];
  const float* ewb  = (const float*)d_in[27];
  float* out = (float*)d_out;

  float* ws   = (float*)d_ws;
  float* w1s  = ws;               // 10240 f
  float* w2s  = w1s + 10240;      // 6144 f
  float* w0s  = w2s + 6144;       // 1024 f
  float* gws0 = w0s + 1024;       // 4096 f
  float* gws1 = gws0 + 4096;      // 8192 f
  float* gws2 = gws1 + 8192;      // 8192 f
  float* ewgs = gws2 + 8192;      // 294912 f (128*64*72 u16)
  float* h0   = ewgs + 294912;    // 499712 f (7808*64 f32)
  float* hBs  = h0 + 499712;      // 499712 f (7808*128 u16 = 999424 u16)
  float* s1p  = hBs + 499712;     // 8192 f
  float* s2p  = s1p + 8192;       // 16384 f
  float* lw0s = s2p + 16384;      // 499712 f (61*128*128 u16)
  float* big  = lw0s + 499712;    // 5496832 f : a0g (conv) then part (mlp) — disjoint lifetimes
  // total ~ 29.4 MB

  u16* w1b    = (u16*)w1s;
  u16* w2b    = (u16*)w2s;
  u16* w0p    = (u16*)w0s;
  u16* gwt0   = (u16*)gws0;
  u16* gwt1   = (u16*)gws1;
  u16* gwt2   = (u16*)gws2;
  u16* ewg_bf = (u16*)ewgs;
  u16* hB     = (u16*)hBs;
  u16* lw0t   = (u16*)lw0s;
  u16* a0g    = (u16*)big;
  float* part = big;

  k_prep  <<<540, 256, 0, stream>>>(cw0, cw1, cw2, gw0, gw1, gw2, lw0,
                                    w0p, w1b, w2b, gwt0, gwt1, gwt2, lw0t);
  k_ewmat <<<NGRAPH, 256, 0, stream>>>(ef, eww, ewb, ewg_bf, out + 512);
  k_conv0 <<<NNODES/4, 256, 0, stream>>>(x, w0p, cb0, a0g);
  k_conv12<<<NNODES/4, 256, 0, stream>>>(a0g, w1b, cb1, w2b, cb2, h0);
  k_stats1<<<64, 256, 0, stream>>>(h0, s1p);
  k_gnn   <<<NGRAPH, 512, 0, stream>>>(h0, s1p, bn1g, bn1b,
                                       gwt0, gb0, gwt1, gb1, gwt2, gb2, ewg_bf, hB);
  k_stats2<<<64, 256, 0, stream>>>(hB, s2p);
  k_mlp0  <<<NPGN*4, 256, 0, stream>>>(hB, s2p, bn2g, bn2b, lw0t, part);
  k_mlp1  <<<NGRAPH, 512, 0, stream>>>(part, lb0, lw1, lb1, lw2, lb2, out);
}